// Round 1
// baseline (1394.876 us; speedup 1.0000x reference)
//
#include <hip/hip_runtime.h>
#include <math.h>

#define BATCH 2
#define SEQ   2048
#define HID   1024
#define NHEAD 16
#define HEADD 64
#define ROWS  (BATCH*SEQ)   // 4096
#define QKV_N (3*HID)       // 3072

// ---------------- C[M,N] = A[M,K] * W[N,K]^T + bias[N] ----------------
template<int BM, int BN, int BK>
__global__ __launch_bounds__(256)
void gemm_bt(const float* __restrict__ A, const float* __restrict__ W,
             const float* __restrict__ bias, float* __restrict__ C,
             int M, int N, int K) {
    __shared__ float As[BM][BK + 1];   // +1 pad: reads are <=2-way bank aliased
    __shared__ float Ws[BN][BK + 1];
    const int tid = threadIdx.x;
    const int tx = tid & 15;           // output col group
    const int ty = tid >> 4;           // output row group
    const long row0 = (long)blockIdx.y * BM;
    const long col0 = (long)blockIdx.x * BN;

    float acc[4][4] = {};

    for (int k0 = 0; k0 < K; k0 += BK) {
        // stage A tile (float4 global loads, scalar LDS writes)
        for (int t = tid; t < BM * (BK / 4); t += 256) {
            int r  = t / (BK / 4);
            int c4 = (t % (BK / 4)) * 4;
            float4 v = *reinterpret_cast<const float4*>(&A[(row0 + r) * K + k0 + c4]);
            As[r][c4 + 0] = v.x; As[r][c4 + 1] = v.y;
            As[r][c4 + 2] = v.z; As[r][c4 + 3] = v.w;
        }
        // stage W tile
        for (int t = tid; t < BN * (BK / 4); t += 256) {
            int r  = t / (BK / 4);
            int c4 = (t % (BK / 4)) * 4;
            float4 v = *reinterpret_cast<const float4*>(&W[(col0 + r) * K + k0 + c4]);
            Ws[r][c4 + 0] = v.x; Ws[r][c4 + 1] = v.y;
            Ws[r][c4 + 2] = v.z; Ws[r][c4 + 3] = v.w;
        }
        __syncthreads();

        #pragma unroll
        for (int kk = 0; kk < BK; ++kk) {
            float a[4], w[4];
            #pragma unroll
            for (int i = 0; i < 4; ++i) a[i] = As[ty * 4 + i][kk];
            #pragma unroll
            for (int j = 0; j < 4; ++j) w[j] = Ws[tx * 4 + j][kk];
            #pragma unroll
            for (int i = 0; i < 4; ++i)
                #pragma unroll
                for (int j = 0; j < 4; ++j)
                    acc[i][j] += a[i] * w[j];
        }
        __syncthreads();
    }

    #pragma unroll
    for (int i = 0; i < 4; ++i) {
        long r = row0 + ty * 4 + i;
        int  c = (int)col0 + tx * 4;
        float4 ov;
        ov.x = acc[i][0] + bias[c + 0];
        ov.y = acc[i][1] + bias[c + 1];
        ov.z = acc[i][2] + bias[c + 2];
        ov.w = acc[i][3] + bias[c + 3];
        *reinterpret_cast<float4*>(&C[r * N + c]) = ov;
    }
}

// ---------------- flash-style attention, fp32 ----------------
// qkv: [ROWS][3072] (Q at +0, K at +1024, V at +2048; head h owns dims h*64..h*64+63)
// o:   [ROWS][1024] attention output, heads re-interleaved
__global__ __launch_bounds__(256)
void attn_kernel(const float* __restrict__ qkv, float* __restrict__ o,
                 const int* __restrict__ use_mask) {
    const int tid = threadIdx.x;
    const int tx = tid & 15;       // head-dim / score-col group
    const int ty = tid >> 4;       // q-row group (16 threads per row set, same wave)
    const int qt = blockIdx.x;     // 0..31  q tile
    const int bh = blockIdx.y;     // 0..31  batch*head
    const int bi = bh >> 4;
    const int h  = bh & 15;
    const int q0 = qt * 64;
    const int causal = use_mask[0];

    __shared__ float Qs [64][65];  // [q_row][d]
    __shared__ float KsT[64][65];  // [d][k_row]   (transposed -> 2-way-free reads)
    __shared__ float Vs [64][65];  // [k_row][d]
    __shared__ float Ss [64][65];  // P tile

    const size_t base = (size_t)bi * SEQ * QKV_N;

    // stage Q once
    for (int t = tid; t < 64 * 16; t += 256) {
        int r  = t >> 4;
        int d4 = (t & 15) * 4;
        float4 v = *reinterpret_cast<const float4*>(
            &qkv[base + (size_t)(q0 + r) * QKV_N + h * HEADD + d4]);
        Qs[r][d4 + 0] = v.x; Qs[r][d4 + 1] = v.y;
        Qs[r][d4 + 2] = v.z; Qs[r][d4 + 3] = v.w;
    }

    float acc[4][4] = {};
    float m_r[4], l_r[4];
    #pragma unroll
    for (int i = 0; i < 4; ++i) { m_r[i] = -INFINITY; l_r[i] = 0.f; }

    for (int kt = 0; kt < SEQ / 64; ++kt) {
        if (causal && kt * 64 > q0 + 63) break;   // tile fully above diagonal
        __syncthreads();                          // prev tile's LDS reads done
        // stage K (transposed) and V
        for (int t = tid; t < 64 * 16; t += 256) {
            int kr = t >> 4;
            int d4 = (t & 15) * 4;
            float4 kv = *reinterpret_cast<const float4*>(
                &qkv[base + (size_t)(kt * 64 + kr) * QKV_N + HID + h * HEADD + d4]);
            KsT[d4 + 0][kr] = kv.x; KsT[d4 + 1][kr] = kv.y;
            KsT[d4 + 2][kr] = kv.z; KsT[d4 + 3][kr] = kv.w;
            float4 vv = *reinterpret_cast<const float4*>(
                &qkv[base + (size_t)(kt * 64 + kr) * QKV_N + 2 * HID + h * HEADD + d4]);
            Vs[kr][d4 + 0] = vv.x; Vs[kr][d4 + 1] = vv.y;
            Vs[kr][d4 + 2] = vv.z; Vs[kr][d4 + 3] = vv.w;
        }
        __syncthreads();

        // S = Q K^T * scale (4x4 per thread)
        float s[4][4] = {};
        #pragma unroll 8
        for (int d = 0; d < 64; ++d) {
            float qv[4], kv[4];
            #pragma unroll
            for (int i = 0; i < 4; ++i) qv[i] = Qs[ty * 4 + i][d];
            #pragma unroll
            for (int j = 0; j < 4; ++j) kv[j] = KsT[d][tx * 4 + j];
            #pragma unroll
            for (int i = 0; i < 4; ++i)
                #pragma unroll
                for (int j = 0; j < 4; ++j)
                    s[i][j] += qv[i] * kv[j];
        }
        #pragma unroll
        for (int i = 0; i < 4; ++i)
            #pragma unroll
            for (int j = 0; j < 4; ++j) {
                float sv = s[i][j] * 0.125f;      // 1/sqrt(64)
                if (causal && (kt * 64 + tx * 4 + j) > (q0 + ty * 4 + i)) sv = -INFINITY;
                s[i][j] = sv;
            }

        // online softmax; the 16 threads of a row are contiguous lanes of one wave
        float new_m[4], corr[4];
        #pragma unroll
        for (int i = 0; i < 4; ++i) {
            float mx = fmaxf(fmaxf(s[i][0], s[i][1]), fmaxf(s[i][2], s[i][3]));
            #pragma unroll
            for (int off = 1; off < 16; off <<= 1) mx = fmaxf(mx, __shfl_xor(mx, off));
            new_m[i] = fmaxf(m_r[i], mx);
            corr[i]  = __expf(m_r[i] - new_m[i]); // -inf - finite -> 0 on first tile
        }
        #pragma unroll
        for (int i = 0; i < 4; ++i) {
            float ssum = 0.f;
            #pragma unroll
            for (int j = 0; j < 4; ++j) {
                float p = __expf(s[i][j] - new_m[i]);
                Ss[ty * 4 + i][tx * 4 + j] = p;
                ssum += p;
            }
            #pragma unroll
            for (int off = 1; off < 16; off <<= 1) ssum += __shfl_xor(ssum, off);
            l_r[i] = l_r[i] * corr[i] + ssum;
            m_r[i] = new_m[i];
            #pragma unroll
            for (int j = 0; j < 4; ++j) acc[i][j] *= corr[i];
        }
        // P (Ss) written & read by the same wave only -> no barrier needed

        // O += P * V
        #pragma unroll 8
        for (int c = 0; c < 64; ++c) {
            float pv[4], vv[4];
            #pragma unroll
            for (int i = 0; i < 4; ++i) pv[i] = Ss[ty * 4 + i][c];
            #pragma unroll
            for (int j = 0; j < 4; ++j) vv[j] = Vs[c][tx * 4 + j];
            #pragma unroll
            for (int i = 0; i < 4; ++i)
                #pragma unroll
                for (int j = 0; j < 4; ++j)
                    acc[i][j] += pv[i] * vv[j];
        }
    }

    #pragma unroll
    for (int i = 0; i < 4; ++i) {
        float inv = 1.0f / l_r[i];
        float4 ov;
        ov.x = acc[i][0] * inv; ov.y = acc[i][1] * inv;
        ov.z = acc[i][2] * inv; ov.w = acc[i][3] * inv;
        *reinterpret_cast<float4*>(
            &o[(size_t)(bi * SEQ + q0 + ty * 4 + i) * HID + h * HEADD + tx * 4]) = ov;
    }
}

extern "C" void kernel_launch(void* const* d_in, const int* in_sizes, int n_in,
                              void* d_out, int out_size, void* d_ws, size_t ws_size,
                              hipStream_t stream) {
    const float* features = (const float*)d_in[0];
    const float* qkv_w    = (const float*)d_in[1];
    const float* qkv_b    = (const float*)d_in[2];
    const float* out_w    = (const float*)d_in[3];
    const float* out_b    = (const float*)d_in[4];
    const int*   use_mask = (const int*)d_in[5];
    float* out = (float*)d_out;

    float* qkv   = (float*)d_ws;                       // [4096][3072]  48 MB
    float* attno = qkv + (size_t)ROWS * QKV_N;         // [4096][1024]  16 MB

    // QKV projection: [4096,1024] @ [3072,1024]^T + b
    dim3 g1(QKV_N / 64, ROWS / 64);
    gemm_bt<64, 64, 32><<<g1, 256, 0, stream>>>(features, qkv_w, qkv_b, qkv,
                                                ROWS, QKV_N, HID);
    // attention
    dim3 g2(SEQ / 64, BATCH * NHEAD);
    attn_kernel<<<g2, 256, 0, stream>>>(qkv, attno, use_mask);

    // output projection: [4096,1024] @ [1024,1024]^T + b
    dim3 g3(HID / 64, ROWS / 64);
    gemm_bt<64, 64, 32><<<g3, 256, 0, stream>>>(attno, out_w, out_b, out,
                                                ROWS, HID, HID);
}

// Round 2
// 200.894 us; speedup vs baseline: 6.9433x; 6.9433x over previous
//
#include <hip/hip_runtime.h>
#include <math.h>

#define BATCH 2
#define SEQ   2048
#define HID   1024
#define NHEAD 16
#define ROWS  (BATCH*SEQ)   // 4096
#define QKV_N (3*HID)       // 3072

typedef __attribute__((ext_vector_type(8))) short bf16x8;   // 8 bf16 in 4 VGPRs
typedef __attribute__((ext_vector_type(4))) float f32x4;

__device__ __forceinline__ unsigned short f2b(float f) {
    unsigned u = __float_as_uint(f);
    u += 0x7FFF + ((u >> 16) & 1);          // round-to-nearest-even
    return (unsigned short)(u >> 16);
}

// global -> LDS direct copy, 16B per lane; LDS dest is wave-uniform base + lane*16
#define GLOAD_LDS16(gp, lp) \
    __builtin_amdgcn_global_load_lds((const __attribute__((address_space(1))) void*)(gp), \
                                     (__attribute__((address_space(3))) void*)(lp), 16, 0, 0)

__global__ __launch_bounds__(256)
void cvt_f32_bf16(const float* __restrict__ in, unsigned short* __restrict__ out, int n4) {
    int i = blockIdx.x * 256 + threadIdx.x;
    if (i >= n4) return;
    float4 v = reinterpret_cast<const float4*>(in)[i];
    ushort4 o;
    o.x = f2b(v.x); o.y = f2b(v.y); o.z = f2b(v.z); o.w = f2b(v.w);
    reinterpret_cast<ushort4*>(out)[i] = o;
}

// ---- C[M,N] = A[M,K] * B[N,K]^T + bias, bf16 inputs, fp32 accum --------------
// MODE 0: f32 output to Cout[M*N]
// MODE 2: qkv mode: cols <2048 -> bf16 Cout (row-major [4096][3072], stride QKV_N);
//         cols >=2048 (V) -> bf16 V^T at vt[(bh*64+d)*2048 + s]
template<int MODE>
__global__ __launch_bounds__(256)
void gemm_mfma(const unsigned short* __restrict__ A, const unsigned short* __restrict__ B,
               const float* __restrict__ bias, void* __restrict__ Cout,
               unsigned short* __restrict__ vt, int M, int N, int K) {
    __shared__ unsigned short As[128 * 32];   // 64B rows, granule-XOR swizzled (row&3)
    __shared__ unsigned short Bs[128 * 32];
    const int tid = threadIdx.x;
    const int w = tid >> 6, l = tid & 63;
    const int wm = w >> 1, wn = w & 1;
    const int l15 = l & 15, l4 = l >> 4;
    const long row0 = (long)blockIdx.y * 128;
    const long col0 = (long)blockIdx.x * 128;

    f32x4 acc[4][4];
    #pragma unroll
    for (int m = 0; m < 4; ++m)
        #pragma unroll
        for (int n = 0; n < 4; ++n) acc[m][n] = (f32x4)0.0f;

    const int lr   = l >> 2;                 // staging row within 16
    const int slot = (l & 3) ^ (lr & 3);     // pre-swizzled source granule

    for (int k0 = 0; k0 < K; k0 += 32) {
        __syncthreads();
        #pragma unroll
        for (int c = 0; c < 2; ++c) {
            int r = w * 32 + c * 16 + lr;
            GLOAD_LDS16(A + (row0 + r) * K + k0 + slot * 8, As + (w * 32 + c * 16) * 32);
            GLOAD_LDS16(B + (col0 + r) * K + k0 + slot * 8, Bs + (w * 32 + c * 16) * 32);
        }
        __syncthreads();

        bf16x8 af[4], bfr[4];
        #pragma unroll
        for (int m = 0; m < 4; ++m) {
            int row = wm * 64 + m * 16 + l15;
            af[m] = *(const bf16x8*)((const char*)As + row * 64 + ((l4 ^ (row & 3)) << 4));
        }
        #pragma unroll
        for (int n = 0; n < 4; ++n) {
            int row = wn * 64 + n * 16 + l15;
            bfr[n] = *(const bf16x8*)((const char*)Bs + row * 64 + ((l4 ^ (row & 3)) << 4));
        }
        #pragma unroll
        for (int m = 0; m < 4; ++m)
            #pragma unroll
            for (int n = 0; n < 4; ++n)
                acc[m][n] = __builtin_amdgcn_mfma_f32_16x16x32_bf16(af[m], bfr[n], acc[m][n], 0, 0, 0);
    }

    #pragma unroll
    for (int m = 0; m < 4; ++m) {
        #pragma unroll
        for (int n = 0; n < 4; ++n) {
            long ccol = col0 + wn * 64 + n * 16 + l15;
            float bv = bias[ccol];
            #pragma unroll
            for (int r2 = 0; r2 < 4; ++r2) {
                long crow = row0 + wm * 64 + m * 16 + l4 * 4 + r2;
                float v = acc[m][n][r2] + bv;
                if (MODE == 0) {
                    ((float*)Cout)[crow * N + ccol] = v;
                } else {
                    if (ccol < 2048) {
                        ((unsigned short*)Cout)[crow * QKV_N + ccol] = f2b(v);
                    } else {
                        long cc = ccol - 2048;
                        long h = cc >> 6, d = cc & 63;
                        long b = crow >> 11, s = crow & 2047;
                        vt[(((b * NHEAD + h) * 64 + d) << 11) + s] = f2b(v);
                    }
                }
            }
        }
    }
}

// ---- flash attention, bf16 MFMA ---------------------------------------------
// qkv: [4096][3072] bf16 (Q cols 0..1023, K cols 1024..2047); vt: [32][64][2048] bf16
// attno: [4096][1024] bf16
__global__ __launch_bounds__(256)
void attn_mfma(const unsigned short* __restrict__ qkv, const unsigned short* __restrict__ vt,
               unsigned short* __restrict__ attno, const int* __restrict__ use_mask) {
    __shared__ unsigned short Ks [64 * 64];   // [token][d], 128B rows, swz(row&7)
    __shared__ unsigned short Vts[64 * 64];   // [d][token], 128B rows, swz(row&7)
    __shared__ unsigned short Ps [4 * 16 * 64]; // per-wave P tile, swz(row&7)
    const int tid = threadIdx.x;
    const int w = tid >> 6, l = tid & 63;
    const int l15 = l & 15, l4 = l >> 4;
    const int qt = blockIdx.x, bh = blockIdx.y;
    const int b = bh >> 4, h = bh & 15;
    const int q0 = qt * 64;
    const int causal = use_mask[0];

    // Q fragments live in registers for the whole block
    bf16x8 qf[2];
    {
        const unsigned short* qp = qkv + (size_t)(b * SEQ + q0 + w * 16 + l15) * QKV_N + h * 64;
        qf[0] = *(const bf16x8*)(qp + l4 * 8);
        qf[1] = *(const bf16x8*)(qp + 32 + l4 * 8);
    }

    f32x4 o_acc[4];
    #pragma unroll
    for (int n = 0; n < 4; ++n) o_acc[n] = (f32x4)0.0f;
    float m_r[4] = {-INFINITY, -INFINITY, -INFINITY, -INFINITY};
    float l_r[4] = {0.f, 0.f, 0.f, 0.f};

    const int srow  = l >> 3;                 // staging row within 8
    const int sslot = (l & 7) ^ (srow & 7);   // pre-swizzled source granule
    const unsigned short* kbase = qkv + (size_t)b * SEQ * QKV_N + HID + h * 64;
    const unsigned short* vbase = vt + (size_t)bh * 64 * SEQ;
    unsigned short* pw = Ps + w * 1024;

    for (int kt = 0; kt < SEQ / 64; ++kt) {
        int kk0 = kt * 64;
        if (causal && kk0 > q0 + 63) break;
        __syncthreads();
        #pragma unroll
        for (int c = 0; c < 2; ++c) {
            int r = w * 16 + c * 8 + srow;
            GLOAD_LDS16(kbase + (size_t)(kk0 + r) * QKV_N + sslot * 8, Ks  + (w * 16 + c * 8) * 64);
            GLOAD_LDS16(vbase + (size_t)r * SEQ + kk0 + sslot * 8,     Vts + (w * 16 + c * 8) * 64);
        }
        __syncthreads();

        // S = Q K^T
        f32x4 s_acc[4];
        #pragma unroll
        for (int n = 0; n < 4; ++n) s_acc[n] = (f32x4)0.0f;
        #pragma unroll
        for (int ks = 0; ks < 2; ++ks) {
            #pragma unroll
            for (int n = 0; n < 4; ++n) {
                int row = n * 16 + l15;
                bf16x8 kf = *(const bf16x8*)((const char*)Ks + row * 128 + (((ks * 4 + l4) ^ (row & 7)) << 4));
                s_acc[n] = __builtin_amdgcn_mfma_f32_16x16x32_bf16(qf[ks], kf, s_acc[n], 0, 0, 0);
            }
        }

        float sv[4][4];
        #pragma unroll
        for (int n = 0; n < 4; ++n)
            #pragma unroll
            for (int r2 = 0; r2 < 4; ++r2) {
                float x = s_acc[n][r2] * 0.125f;   // 1/sqrt(64)
                if (causal) {
                    int col  = kk0 + n * 16 + l15;
                    int rowq = q0 + w * 16 + l4 * 4 + r2;
                    if (col > rowq) x = -INFINITY;
                }
                sv[n][r2] = x;
            }

        // online softmax; row r2 is shared by the 16 lanes with equal l>>4
        float corr[4];
        #pragma unroll
        for (int r2 = 0; r2 < 4; ++r2) {
            float mx = fmaxf(fmaxf(sv[0][r2], sv[1][r2]), fmaxf(sv[2][r2], sv[3][r2]));
            #pragma unroll
            for (int off = 1; off < 16; off <<= 1) mx = fmaxf(mx, __shfl_xor(mx, off));
            float nm = fmaxf(m_r[r2], mx);
            corr[r2] = __expf(m_r[r2] - nm);       // first tile: exp(-inf)=0
            m_r[r2] = nm;
        }

        float rs[4] = {0.f, 0.f, 0.f, 0.f};
        #pragma unroll
        for (int n = 0; n < 4; ++n) {
            #pragma unroll
            for (int r2 = 0; r2 < 4; ++r2) {
                float p = __expf(sv[n][r2] - m_r[r2]);   // masked: exp(-inf)=0
                rs[r2] += p;
                int prow = l4 * 4 + r2;
                int pofs = (n * 16 + l15) * 2;
                *(unsigned short*)((char*)pw + prow * 128 + (pofs ^ ((prow & 7) << 4))) = f2b(p);
            }
        }
        #pragma unroll
        for (int r2 = 0; r2 < 4; ++r2) {
            float t = rs[r2];
            #pragma unroll
            for (int off = 1; off < 16; off <<= 1) t += __shfl_xor(t, off);
            l_r[r2] = l_r[r2] * corr[r2] + t;
            #pragma unroll
            for (int n = 0; n < 4; ++n) o_acc[n][r2] *= corr[r2];
        }

        // O += P V   (P written+read by same wave -> no barrier)
        #pragma unroll
        for (int ks = 0; ks < 2; ++ks) {
            bf16x8 pf = *(const bf16x8*)((const char*)pw + l15 * 128 + (((ks * 4 + l4) ^ (l15 & 7)) << 4));
            #pragma unroll
            for (int n = 0; n < 4; ++n) {
                int vrow = n * 16 + l15;
                bf16x8 vf = *(const bf16x8*)((const char*)Vts + vrow * 128 + (((ks * 4 + l4) ^ (vrow & 7)) << 4));
                o_acc[n] = __builtin_amdgcn_mfma_f32_16x16x32_bf16(pf, vf, o_acc[n], 0, 0, 0);
            }
        }
    }

    #pragma unroll
    for (int r2 = 0; r2 < 4; ++r2) {
        float inv = 1.0f / l_r[r2];
        size_t orow = (size_t)(b * SEQ + q0 + w * 16 + l4 * 4 + r2);
        #pragma unroll
        for (int n = 0; n < 4; ++n)
            attno[orow * HID + h * 64 + n * 16 + l15] = f2b(o_acc[n][r2] * inv);
    }
}

extern "C" void kernel_launch(void* const* d_in, const int* in_sizes, int n_in,
                              void* d_out, int out_size, void* d_ws, size_t ws_size,
                              hipStream_t stream) {
    const float* features = (const float*)d_in[0];
    const float* qkv_w    = (const float*)d_in[1];
    const float* qkv_b    = (const float*)d_in[2];
    const float* out_w    = (const float*)d_in[3];
    const float* out_b    = (const float*)d_in[4];
    const int*   use_mask = (const int*)d_in[5];

    char* ws = (char*)d_ws;
    unsigned short* fbf     = (unsigned short*)(ws);              // 8 MB  features bf16
    unsigned short* wbf     = (unsigned short*)(ws + 8388608);    // 6 MB  qkv_w bf16
    unsigned short* owbf    = (unsigned short*)(ws + 14680064);   // 2 MB  out_w bf16
    unsigned short* qkvbf   = (unsigned short*)(ws + 16777216);   // 24 MB qkv bf16 (Q,K used)
    unsigned short* vtbuf   = (unsigned short*)(ws + 41943040);   // 8 MB  V^T bf16
    unsigned short* attnobf = (unsigned short*)(ws + 50331648);   // 8 MB  attn out bf16

    cvt_f32_bf16<<<4096, 256, 0, stream>>>(features, fbf, 1048576);
    cvt_f32_bf16<<<3072, 256, 0, stream>>>(qkv_w, wbf, 786432);
    cvt_f32_bf16<<<1024, 256, 0, stream>>>(out_w, owbf, 262144);

    dim3 g1(QKV_N / 128, ROWS / 128);   // (24, 32)
    gemm_mfma<2><<<g1, 256, 0, stream>>>(fbf, wbf, qkv_b, (void*)qkvbf, vtbuf,
                                         ROWS, QKV_N, HID);
    dim3 g2(SEQ / 64, BATCH * NHEAD);   // (32, 32)
    attn_mfma<<<g2, 256, 0, stream>>>(qkvbf, vtbuf, attnobf, use_mask);

    dim3 g3(HID / 128, ROWS / 128);     // (8, 32)
    gemm_mfma<0><<<g3, 256, 0, stream>>>(attnobf, owbf, out_b, d_out, (unsigned short*)nullptr,
                                         ROWS, HID, HID);
}